// Round 6
// baseline (1990.028 us; speedup 1.0000x reference)
//
#include <hip/hip_runtime.h>
#include <hip/hip_bf16.h>
#include <stddef.h>

// Problem constants (fixed by harness)
constexpr int N    = 100000;
constexpr int E    = 1600000;
constexpr int F_IN = 128;
constexpr int H    = 64;
constexpr int C    = 16;
constexpr float BN_EPS = 1e-5f;

// Bucketed-aggregation geometry
constexpr int TILE  = 128;                      // nodes per bucket
constexpr int NB    = (N + TILE - 1) / TILE;    // 782 buckets
constexpr int CAP   = 2816;                     // slots/bucket (lambda=2048, +17 sigma)
constexpr int CHUNK = 8192;                     // edges per binfill block
constexpr int FBLK  = (E + CHUNK - 1) / CHUNK;  // 196

#define DEV __device__ __forceinline__

DEV float elu_f(float x) { return x > 0.f ? x : (expf(x) - 1.f); }

// ---------------------------------------------------------------------------
// Bucket cursor init: gcur[b] = b * CAP
// ---------------------------------------------------------------------------
__global__ void k_initcur(int* __restrict__ gcur) {
    int i = threadIdx.x + blockIdx.x * blockDim.x;
    if (i < NB) gcur[i] = i * CAP;
}

// ---------------------------------------------------------------------------
// Binned fill: partition edges into 782 dst-range buckets.
// Per block: LDS histogram -> one bulk global reservation per bucket ->
// scatter packed (src | dstLocal<<17) as contiguous runs (kills the 16x
// write-allocate amplification the per-edge atomic CSR fill had).
// ---------------------------------------------------------------------------
__global__ __launch_bounds__(256) void k_binfill(const int* __restrict__ esrc,
                                                 const int* __restrict__ edst,
                                                 int* __restrict__ gcur,
                                                 int* __restrict__ ebuf) {
    __shared__ int lcnt[NB];   // pass1: counts; pass3: local cursors
    __shared__ int lbase[NB];  // reserved global base per bucket
    const int t    = threadIdx.x;
    const int cbeg = blockIdx.x * CHUNK;
    const int cend = (cbeg + CHUNK < E) ? cbeg + CHUNK : E;

    for (int i = t; i < NB; i += 256) lcnt[i] = 0;
    __syncthreads();
    for (int i = cbeg + t; i < cend; i += 256)
        atomicAdd(&lcnt[edst[i] >> 7], 1);
    __syncthreads();
    for (int i = t; i < NB; i += 256) {
        int c = lcnt[i];
        lbase[i] = c ? atomicAdd(&gcur[i], c) : 0;
    }
    __syncthreads();
    for (int i = t; i < NB; i += 256) lcnt[i] = 0;
    __syncthreads();
    for (int i = cbeg + t; i < cend; i += 256) {
        int d = edst[i], s = esrc[i];
        int b = d >> 7;
        int pos = lbase[b] + atomicAdd(&lcnt[b], 1);
        ebuf[pos] = s | ((d & (TILE - 1)) << 17);   // src:17b | dstLocal:7b
    }
}

// ---------------------------------------------------------------------------
// Bucketed aggregation + fused BN-stats partials:
//   z[n][f] = y[n][f] + sum_{s->n} y[s][f] + bias[f]
//   part[b][f]    = sum_n z[n][f]   (this bucket)
//   part[b][64+f] = sum_n z[n][f]^2
// One block per 128-node bucket; 32KB LDS accumulator [node][feat].
// 4 waves stream the packed edge list: 64 indices per coalesced load,
// broadcast via __shfl, 8 gathers in flight, LDS atomic f32 accumulate
// (addr % 64 == lane -> bank-conflict-free).
// ---------------------------------------------------------------------------
__global__ __launch_bounds__(256) void k_aggb(const float* __restrict__ y,
                                              const int* __restrict__ ebuf,
                                              const int* __restrict__ gcur,
                                              const float* __restrict__ bias,
                                              float* __restrict__ z,
                                              float* __restrict__ part) {
    __shared__ float acc[TILE * 64];  // 32 KB
    const int t    = threadIdx.x;
    const int lane = t & 63;
    const int w    = t >> 6;
    const int b    = blockIdx.x;

    for (int i = t * 4; i < TILE * 64; i += 1024)
        *reinterpret_cast<float4*>(&acc[i]) = float4{0.f, 0.f, 0.f, 0.f};
    __syncthreads();

    const int beg = b * CAP;
    int end = gcur[b];
    if (end > beg + CAP) end = beg + CAP;  // defensive clamp

    for (int cb = beg + w * 64; cb < end; cb += 256) {
        int nk = end - cb; if (nk > 64) nk = 64;
        int pack = (lane < nk) ? ebuf[cb + lane] : 0;
        int k = 0;
        for (; k + 8 <= nk; k += 8) {
            int p0 = __shfl(pack, k + 0);
            int p1 = __shfl(pack, k + 1);
            int p2 = __shfl(pack, k + 2);
            int p3 = __shfl(pack, k + 3);
            int p4 = __shfl(pack, k + 4);
            int p5 = __shfl(pack, k + 5);
            int p6 = __shfl(pack, k + 6);
            int p7 = __shfl(pack, k + 7);
            float v0 = y[(size_t)(p0 & 0x1FFFF) * 64 + lane];
            float v1 = y[(size_t)(p1 & 0x1FFFF) * 64 + lane];
            float v2 = y[(size_t)(p2 & 0x1FFFF) * 64 + lane];
            float v3 = y[(size_t)(p3 & 0x1FFFF) * 64 + lane];
            float v4 = y[(size_t)(p4 & 0x1FFFF) * 64 + lane];
            float v5 = y[(size_t)(p5 & 0x1FFFF) * 64 + lane];
            float v6 = y[(size_t)(p6 & 0x1FFFF) * 64 + lane];
            float v7 = y[(size_t)(p7 & 0x1FFFF) * 64 + lane];
            atomicAdd(&acc[(p0 >> 17) * 64 + lane], v0);
            atomicAdd(&acc[(p1 >> 17) * 64 + lane], v1);
            atomicAdd(&acc[(p2 >> 17) * 64 + lane], v2);
            atomicAdd(&acc[(p3 >> 17) * 64 + lane], v3);
            atomicAdd(&acc[(p4 >> 17) * 64 + lane], v4);
            atomicAdd(&acc[(p5 >> 17) * 64 + lane], v5);
            atomicAdd(&acc[(p6 >> 17) * 64 + lane], v6);
            atomicAdd(&acc[(p7 >> 17) * 64 + lane], v7);
        }
        for (; k < nk; ++k) {
            int p = __shfl(pack, k);
            atomicAdd(&acc[(p >> 17) * 64 + lane], y[(size_t)(p & 0x1FFFF) * 64 + lane]);
        }
    }
    __syncthreads();

    // Epilogue: self-term + bias -> z, accumulating per-lane BN partials.
    const float bf = bias[lane];
    float psum = 0.f, psq = 0.f;
#pragma unroll 4
    for (int i = 0; i < TILE / 4; ++i) {   // wave w owns nodes [w*32, w*32+32)
        int n  = w * 32 + i;
        int gn = b * TILE + n;
        if (gn < N) {
            float v = acc[n * 64 + lane] + y[(size_t)gn * 64 + lane] + bf;
            z[(size_t)gn * 64 + lane] = v;
            psum += v;
            psq  += v * v;
        }
    }
    __syncthreads();                       // done reading acc; reuse for reduce
    acc[w * 64 + lane]       = psum;
    acc[256 + w * 64 + lane] = psq;
    __syncthreads();
    if (t < 64) {
        part[(size_t)b * 128 + lane] =
            acc[lane] + acc[64 + lane] + acc[128 + lane] + acc[192 + lane];
        part[(size_t)b * 128 + 64 + lane] =
            acc[256 + lane] + acc[320 + lane] + acc[384 + lane] + acc[448 + lane];
    }
}

// ---------------------------------------------------------------------------
// BN finalize: reduce NB per-bucket partials -> scale/shift
// ---------------------------------------------------------------------------
__global__ void k_stats2(const float* __restrict__ part, const float* __restrict__ g,
                         const float* __restrict__ be, float* __restrict__ scale,
                         float* __restrict__ shift) {
    __shared__ float lds[128];
    int t = threadIdx.x;  // 128 threads
    float s = 0.f;
#pragma unroll 4
    for (int b = 0; b < NB; ++b) s += part[(size_t)b * 128 + t];
    lds[t] = s;
    __syncthreads();
    if (t < 64) {
        float mu   = lds[t] * (1.f / N);
        float var  = lds[64 + t] * (1.f / N) - mu * mu;
        float rstd = rsqrtf(var + BN_EPS);
        float sc   = rstd * g[t];
        scale[t] = sc;
        shift[t] = be[t] - mu * sc;
    }
}

// ---------------------------------------------------------------------------
// Linear: out[N,64] = act( in'[N,K] @ W[K,64] (+bias) ), in' = optional BN+ELU
// lane = node row; acc[64] fully static-indexed (stays in VGPRs, rule #20).
// ---------------------------------------------------------------------------
template <int K, bool BN_IN, bool ELU_OUT, bool BIAS>
__global__ __launch_bounds__(256) void k_linear(const float* __restrict__ in,
                                                const float* __restrict__ W,
                                                const float* __restrict__ bias,
                                                const float* __restrict__ scale,
                                                const float* __restrict__ shift,
                                                float* __restrict__ out) {
    const int lane = threadIdx.x & 63;
    const int wid  = (blockIdx.x * blockDim.x + threadIdx.x) >> 6;
    const int row  = wid * 64 + lane;
    if (row >= N) return;

    float acc[64];
#pragma unroll
    for (int f = 0; f < 64; ++f) acc[f] = BIAS ? bias[f] : 0.f;

    const float* xr = in + (size_t)row * K;

#pragma unroll 2
    for (int k4 = 0; k4 < K / 4; ++k4) {
        float4 xv = *reinterpret_cast<const float4*>(xr + k4 * 4);
        if (BN_IN) {
            const int c = k4 * 4;  // uniform
            xv.x = elu_f(xv.x * scale[c + 0] + shift[c + 0]);
            xv.y = elu_f(xv.y * scale[c + 1] + shift[c + 1]);
            xv.z = elu_f(xv.z * scale[c + 2] + shift[c + 2]);
            xv.w = elu_f(xv.w * scale[c + 3] + shift[c + 3]);
        }
#pragma unroll
        for (int j = 0; j < 4; ++j) {
            const float xk = (j == 0) ? xv.x : (j == 1) ? xv.y : (j == 2) ? xv.z : xv.w;
            const float4* Wk = reinterpret_cast<const float4*>(W + (size_t)(k4 * 4 + j) * 64);
#pragma unroll
            for (int f4 = 0; f4 < 16; ++f4) {
                float4 w = Wk[f4];
                acc[f4 * 4 + 0] = fmaf(xk, w.x, acc[f4 * 4 + 0]);
                acc[f4 * 4 + 1] = fmaf(xk, w.y, acc[f4 * 4 + 1]);
                acc[f4 * 4 + 2] = fmaf(xk, w.z, acc[f4 * 4 + 2]);
                acc[f4 * 4 + 3] = fmaf(xk, w.w, acc[f4 * 4 + 3]);
            }
        }
    }

    float* orow = out + (size_t)row * 64;
#pragma unroll
    for (int f4 = 0; f4 < 16; ++f4) {
        float4 v;
        v.x = ELU_OUT ? elu_f(acc[f4 * 4 + 0]) : acc[f4 * 4 + 0];
        v.y = ELU_OUT ? elu_f(acc[f4 * 4 + 1]) : acc[f4 * 4 + 1];
        v.z = ELU_OUT ? elu_f(acc[f4 * 4 + 2]) : acc[f4 * 4 + 2];
        v.w = ELU_OUT ? elu_f(acc[f4 * 4 + 3]) : acc[f4 * 4 + 3];
        *reinterpret_cast<float4*>(orow + f4 * 4) = v;
    }
}

// ---------------------------------------------------------------------------
// Head: out = relu([h1,h2] @ Wl1 + bl1) @ Wl2 + bl2
// lane = row; all acc[] indices compile-time static (rule #20).
// ---------------------------------------------------------------------------
__global__ __launch_bounds__(256) void k_final(const float* __restrict__ h1,
                                               const float* __restrict__ h2,
                                               const float* __restrict__ Wl1,
                                               const float* __restrict__ bl1,
                                               const float* __restrict__ Wl2,
                                               const float* __restrict__ bl2,
                                               float* __restrict__ out) {
    const int lane = threadIdx.x & 63;
    const int wid  = (blockIdx.x * blockDim.x + threadIdx.x) >> 6;
    const int row  = wid * 64 + lane;
    if (row >= N) return;

    float acc[64];
#pragma unroll
    for (int f = 0; f < 64; ++f) acc[f] = bl1[f];

#pragma unroll 1
    for (int half = 0; half < 2; ++half) {
        const float* xr = (half == 0 ? h1 : h2) + (size_t)row * 64;
        const float* Wh = Wl1 + (size_t)half * 64 * 64;
#pragma unroll 2
        for (int k4 = 0; k4 < 16; ++k4) {
            float4 xv = *reinterpret_cast<const float4*>(xr + k4 * 4);
#pragma unroll
            for (int j = 0; j < 4; ++j) {
                const float xk = (j == 0) ? xv.x : (j == 1) ? xv.y : (j == 2) ? xv.z : xv.w;
                const float4* Wk = reinterpret_cast<const float4*>(Wh + (size_t)(k4 * 4 + j) * 64);
#pragma unroll
                for (int f4 = 0; f4 < 16; ++f4) {
                    float4 w = Wk[f4];
                    acc[f4 * 4 + 0] = fmaf(xk, w.x, acc[f4 * 4 + 0]);
                    acc[f4 * 4 + 1] = fmaf(xk, w.y, acc[f4 * 4 + 1]);
                    acc[f4 * 4 + 2] = fmaf(xk, w.z, acc[f4 * 4 + 2]);
                    acc[f4 * 4 + 3] = fmaf(xk, w.w, acc[f4 * 4 + 3]);
                }
            }
        }
    }

    float acc2[16];
#pragma unroll
    for (int c = 0; c < 16; ++c) acc2[c] = bl2[c];
#pragma unroll
    for (int k = 0; k < 64; ++k) {
        float tk = fmaxf(acc[k], 0.f);
        const float4* Wk = reinterpret_cast<const float4*>(Wl2 + (size_t)k * 16);
#pragma unroll
        for (int c4 = 0; c4 < 4; ++c4) {
            float4 w = Wk[c4];
            acc2[c4 * 4 + 0] = fmaf(tk, w.x, acc2[c4 * 4 + 0]);
            acc2[c4 * 4 + 1] = fmaf(tk, w.y, acc2[c4 * 4 + 1]);
            acc2[c4 * 4 + 2] = fmaf(tk, w.z, acc2[c4 * 4 + 2]);
            acc2[c4 * 4 + 3] = fmaf(tk, w.w, acc2[c4 * 4 + 3]);
        }
    }

    float* orow = out + (size_t)row * 16;
#pragma unroll
    for (int c4 = 0; c4 < 4; ++c4) {
        float4 v;
        v.x = acc2[c4 * 4 + 0];
        v.y = acc2[c4 * 4 + 1];
        v.z = acc2[c4 * 4 + 2];
        v.w = acc2[c4 * 4 + 3];
        *reinterpret_cast<float4*>(orow + c4 * 4) = v;
    }
}

// ---------------------------------------------------------------------------
// Launch
// ---------------------------------------------------------------------------
extern "C" void kernel_launch(void* const* d_in, const int* in_sizes, int n_in,
                              void* d_out, int out_size, void* d_ws, size_t ws_size,
                              hipStream_t stream) {
    const float* x   = (const float*)d_in[0];
    const int*   ei  = (const int*)d_in[1];
    const int*   esrc = ei;       // edge_index[0]
    const int*   edst = ei + E;   // edge_index[1]
    const float* W1  = (const float*)d_in[2];
    const float* b1  = (const float*)d_in[3];
    const float* g1  = (const float*)d_in[4];
    const float* be1 = (const float*)d_in[5];
    const float* W2  = (const float*)d_in[6];
    const float* b2  = (const float*)d_in[7];
    const float* W3  = (const float*)d_in[8];
    const float* b3  = (const float*)d_in[9];
    const float* g2  = (const float*)d_in[10];
    const float* be2 = (const float*)d_in[11];
    const float* W4  = (const float*)d_in[12];
    const float* b4  = (const float*)d_in[13];
    const float* Wl1 = (const float*)d_in[14];
    const float* bl1 = (const float*)d_in[15];
    const float* Wl2 = (const float*)d_in[16];
    const float* bl2 = (const float*)d_in[17];
    float* out = (float*)d_out;

    // Workspace carve (aligned 256B)
    char* p = (char*)d_ws;
    auto carve = [&](size_t bytes) {
        void* r = (void*)p;
        p += (bytes + 255) & ~(size_t)255;
        return r;
    };
    constexpr size_t SROW = (size_t)N * H * sizeof(float);  // 25.6 MB
    float* y   = (float*)carve(SROW);
    float* z   = (float*)carve(SROW);
    float* h1  = (float*)carve(SROW);
    float* h2  = (float*)carve(SROW);
    int*   ebuf = (int*)carve((size_t)NB * CAP * 4);        // 8.8 MB
    int*   gcur = (int*)carve((size_t)NB * 4);
    float* part  = (float*)carve((size_t)NB * 128 * 4);     // 400 KB
    float* scale = (float*)carve(64 * 4);
    float* shift = (float*)carve(64 * 4);
    (void)ws_size; (void)in_sizes; (void)n_in; (void)out_size;

    constexpr int LINB = ((N + 63) / 64 + 3) / 4;  // 391 blocks of 4 waves

    // Bucketed edge binning (built once, reused by both layers)
    k_initcur<<<1, 1024, 0, stream>>>(gcur);
    k_binfill<<<FBLK, 256, 0, stream>>>(esrc, edst, gcur, ebuf);

    // Layer 1: y = x@W1 ; z = y + agg(y) + b1 (+stats) ; h1 = elu(bnelu(z)@W2 + b2)
    k_linear<128, false, false, false><<<LINB, 256, 0, stream>>>(x, W1, nullptr, nullptr, nullptr, y);
    k_aggb<<<NB, 256, 0, stream>>>(y, ebuf, gcur, b1, z, part);
    k_stats2<<<1, 128, 0, stream>>>(part, g1, be1, scale, shift);
    k_linear<64, true, true, true><<<LINB, 256, 0, stream>>>(z, W2, b2, scale, shift, h1);

    // Layer 2
    k_linear<64, false, false, false><<<LINB, 256, 0, stream>>>(h1, W3, nullptr, nullptr, nullptr, y);
    k_aggb<<<NB, 256, 0, stream>>>(y, ebuf, gcur, b3, z, part);
    k_stats2<<<1, 128, 0, stream>>>(part, g2, be2, scale, shift);
    k_linear<64, true, true, true><<<LINB, 256, 0, stream>>>(z, W4, b4, scale, shift, h2);

    // Head
    k_final<<<LINB, 256, 0, stream>>>(h1, h2, Wl1, bl1, Wl2, bl2, out);
}

// Round 11
// 581.017 us; speedup vs baseline: 3.4251x; 3.4251x over previous
//
#include <hip/hip_runtime.h>
#include <hip/hip_bf16.h>
#include <stddef.h>

// Problem constants (fixed by harness)
constexpr int N    = 100000;
constexpr int E    = 1600000;
constexpr int F_IN = 128;
constexpr int H    = 64;
constexpr int C    = 16;
constexpr float BN_EPS = 1e-5f;

// Bucket geometry (for CSR construction only — agg runs wave-per-node)
constexpr int TILE  = 128;                      // nodes per bucket
constexpr int NB    = (N + TILE - 1) / TILE;    // 782 buckets
constexpr int CAP   = 2816;                     // slots/bucket (lambda~2048, +17 sigma)
constexpr int CHUNK = 8192;                     // edges per binfill block
constexpr int FBLK  = (E + CHUNK - 1) / CHUNK;  // 196

#define DEV __device__ __forceinline__

DEV float elu_f(float x) { return x > 0.f ? x : (expf(x) - 1.f); }

// ---------------------------------------------------------------------------
// Bucket cursor init: gcur[b] = b * CAP
// ---------------------------------------------------------------------------
__global__ void k_initcur(int* __restrict__ gcur) {
    int i = threadIdx.x + blockIdx.x * blockDim.x;
    if (i < NB) gcur[i] = i * CAP;
}

// ---------------------------------------------------------------------------
// Binned fill (validated R6): partition edges into 782 dst-range buckets.
// LDS histogram -> one bulk reservation per (block,bucket) -> contiguous-run
// packed writes. Kills k_fill's 16x write-allocate amplification (105MB->13MB).
// ---------------------------------------------------------------------------
__global__ __launch_bounds__(256) void k_binfill(const int* __restrict__ esrc,
                                                 const int* __restrict__ edst,
                                                 int* __restrict__ gcur,
                                                 int* __restrict__ ebuf) {
    __shared__ int lcnt[NB];   // pass1: counts; pass3: local cursors
    __shared__ int lbase[NB];  // reserved global base per bucket
    const int t    = threadIdx.x;
    const int cbeg = blockIdx.x * CHUNK;
    const int cend = (cbeg + CHUNK < E) ? cbeg + CHUNK : E;

    for (int i = t; i < NB; i += 256) lcnt[i] = 0;
    __syncthreads();
    for (int i = cbeg + t; i < cend; i += 256)
        atomicAdd(&lcnt[edst[i] >> 7], 1);
    __syncthreads();
    for (int i = t; i < NB; i += 256) {
        int c = lcnt[i];
        lbase[i] = c ? atomicAdd(&gcur[i], c) : 0;
    }
    __syncthreads();
    for (int i = t; i < NB; i += 256) lcnt[i] = 0;
    __syncthreads();
    for (int i = cbeg + t; i < cend; i += 256) {
        int d = edst[i], s = esrc[i];
        int b = d >> 7;
        int pos = lbase[b] + atomicAdd(&lcnt[b], 1);
        ebuf[pos] = s | ((d & (TILE - 1)) << 17);   // src:17b | dstLocal:7b
    }
}

// ---------------------------------------------------------------------------
// Bucket-count exclusive scan (1 block): bbase[b] = sum_{b'<b} cnt[b'],
// also writes row_ptr[N] = E.
// ---------------------------------------------------------------------------
__global__ __launch_bounds__(1024) void k_bscan(const int* __restrict__ gcur,
                                                int* __restrict__ bbase,
                                                int* __restrict__ row_ptr) {
    __shared__ int sc[1024];
    int t = threadIdx.x;
    int cnt = (t < NB) ? (gcur[t] - t * CAP) : 0;
    sc[t] = cnt;
    __syncthreads();
    for (int off = 1; off < 1024; off <<= 1) {
        int v = (t >= off) ? sc[t - off] : 0;
        __syncthreads();
        sc[t] += v;
        __syncthreads();
    }
    if (t < NB) bbase[t] = sc[t] - cnt;   // exclusive
    if (t == 0) row_ptr[N] = E;
}

// ---------------------------------------------------------------------------
// Per-bucket counting sort -> CSR. One block per bucket. All scatter
// traffic confined to an LDS-cursored window -> contiguous-ish writes.
// Emits row_ptr for the bucket's 128 nodes.
// ---------------------------------------------------------------------------
__global__ __launch_bounds__(256) void k_bsort(const int* __restrict__ ebuf,
                                               const int* __restrict__ gcur,
                                               const int* __restrict__ bbase,
                                               int* __restrict__ row_ptr,
                                               int* __restrict__ csr_src) {
    __shared__ int hist[TILE];   // original per-node counts
    __shared__ int sc[TILE];     // inclusive scan
    __shared__ int cur[TILE];    // scatter cursors (exclusive offsets)
    const int t   = threadIdx.x;
    const int b   = blockIdx.x;
    const int beg = b * CAP;
    const int cnt = gcur[b] - beg;
    const int gb  = bbase[b];

    if (t < TILE) hist[t] = 0;
    __syncthreads();
    for (int i = t; i < cnt; i += 256)
        atomicAdd(&hist[(ebuf[beg + i] >> 17) & (TILE - 1)], 1);
    __syncthreads();
    if (t < TILE) sc[t] = hist[t];
    __syncthreads();
    for (int off = 1; off < TILE; off <<= 1) {
        int v = (t < TILE && t >= off) ? sc[t - off] : 0;
        __syncthreads();
        if (t < TILE) sc[t] += v;
        __syncthreads();
    }
    if (t < TILE) {
        int excl = sc[t] - hist[t];
        cur[t] = excl;
        int gn = b * TILE + t;
        if (gn < N) row_ptr[gn] = gb + excl;
    }
    __syncthreads();
    for (int i = t; i < cnt; i += 256) {
        int pack = ebuf[beg + i];
        int dl   = (pack >> 17) & (TILE - 1);
        int pos  = gb + atomicAdd(&cur[dl], 1);
        csr_src[pos] = pack & 0x1FFFF;
    }
}

// ---------------------------------------------------------------------------
// Aggregation (proven structure): z[n][f] = y[n][f] + sum_{s->n} y[s][f] + b[f]
// One wave per node (full occupancy: 25K blocks, no LDS), lane = feature.
// Neighbor indices fetched in one parallel load, broadcast from registers
// via __shfl; gather loop unrolled x8 -> 8 independent 256B gathers in flight.
// ---------------------------------------------------------------------------
__global__ __launch_bounds__(256) void k_agg(const float* __restrict__ y,
                                             const int* __restrict__ row_ptr,
                                             const int* __restrict__ csr_src,
                                             const float* __restrict__ bias,
                                             float* __restrict__ z) {
    int wid  = (blockIdx.x * blockDim.x + threadIdx.x) >> 6;
    int lane = threadIdx.x & 63;
    if (wid >= N) return;
    float self = y[(size_t)wid * 64 + lane];          // issue early
    int beg = __builtin_amdgcn_readfirstlane(row_ptr[wid]);
    int end = __builtin_amdgcn_readfirstlane(row_ptr[wid + 1]);
    int deg = end - beg;
    int myidx = (lane < deg) ? csr_src[beg + lane] : 0;

    float acc = self + bias[lane];
    int d64 = deg < 64 ? deg : 64;
    int k = 0;
    for (; k + 8 <= d64; k += 8) {
        int s0 = __shfl(myidx, k + 0);
        int s1 = __shfl(myidx, k + 1);
        int s2 = __shfl(myidx, k + 2);
        int s3 = __shfl(myidx, k + 3);
        int s4 = __shfl(myidx, k + 4);
        int s5 = __shfl(myidx, k + 5);
        int s6 = __shfl(myidx, k + 6);
        int s7 = __shfl(myidx, k + 7);
        float v0 = y[(size_t)s0 * 64 + lane];
        float v1 = y[(size_t)s1 * 64 + lane];
        float v2 = y[(size_t)s2 * 64 + lane];
        float v3 = y[(size_t)s3 * 64 + lane];
        float v4 = y[(size_t)s4 * 64 + lane];
        float v5 = y[(size_t)s5 * 64 + lane];
        float v6 = y[(size_t)s6 * 64 + lane];
        float v7 = y[(size_t)s7 * 64 + lane];
        acc += v0; acc += v1; acc += v2; acc += v3;
        acc += v4; acc += v5; acc += v6; acc += v7;
    }
    for (; k < d64; ++k) {
        int s = __shfl(myidx, k);
        acc += y[(size_t)s * 64 + lane];
    }
    for (int kk = beg + 64; kk < end; ++kk) {        // rare: degree > 64
        int s = csr_src[kk];
        acc += y[(size_t)s * 64 + lane];
    }
    z[(size_t)wid * 64 + lane] = acc;
}

// ---------------------------------------------------------------------------
// BN stats: per-block partial sums/sumsq per feature -> finalize scale/shift
// ---------------------------------------------------------------------------
__global__ __launch_bounds__(256) void k_stats1(const float* __restrict__ z,
                                                float* __restrict__ part) {
    __shared__ float s1[256], s2[256];
    int t = threadIdx.x;
    int f = t & 63, g = t >> 6;
    float sum = 0.f, sq = 0.f;
    for (int r = blockIdx.x * 4 + g; r < N; r += gridDim.x * 4) {
        float v = z[(size_t)r * 64 + f];
        sum += v;
        sq  += v * v;
    }
    s1[t] = sum; s2[t] = sq;
    __syncthreads();
    if (t < 128) { s1[t] += s1[t + 128]; s2[t] += s2[t + 128]; }
    __syncthreads();
    if (t < 64) {
        part[blockIdx.x * 128 + t]      = s1[t] + s1[t + 64];
        part[blockIdx.x * 128 + 64 + t] = s2[t] + s2[t + 64];
    }
}

__global__ void k_stats2(const float* __restrict__ part, const float* __restrict__ g,
                         const float* __restrict__ be, float* __restrict__ scale,
                         float* __restrict__ shift) {
    __shared__ float lds[128];
    int t = threadIdx.x;  // 128 threads
    float s = 0.f;
    for (int b = 0; b < 256; ++b) s += part[b * 128 + t];
    lds[t] = s;
    __syncthreads();
    if (t < 64) {
        float mu   = lds[t] * (1.f / N);
        float var  = lds[64 + t] * (1.f / N) - mu * mu;
        float rstd = rsqrtf(var + BN_EPS);
        float sc   = rstd * g[t];
        scale[t] = sc;
        shift[t] = be[t] - mu * sc;
    }
}

// ---------------------------------------------------------------------------
// Linear: out[N,64] = act( in'[N,K] @ W[K,64] (+bias) ), in' = optional BN+ELU
// lane = node row; acc[64] fully static-indexed (stays in VGPRs, rule #20).
// ---------------------------------------------------------------------------
template <int K, bool BN_IN, bool ELU_OUT, bool BIAS>
__global__ __launch_bounds__(256) void k_linear(const float* __restrict__ in,
                                                const float* __restrict__ W,
                                                const float* __restrict__ bias,
                                                const float* __restrict__ scale,
                                                const float* __restrict__ shift,
                                                float* __restrict__ out) {
    const int lane = threadIdx.x & 63;
    const int wid  = (blockIdx.x * blockDim.x + threadIdx.x) >> 6;
    const int row  = wid * 64 + lane;
    if (row >= N) return;

    float acc[64];
#pragma unroll
    for (int f = 0; f < 64; ++f) acc[f] = BIAS ? bias[f] : 0.f;

    const float* xr = in + (size_t)row * K;

#pragma unroll 2
    for (int k4 = 0; k4 < K / 4; ++k4) {
        float4 xv = *reinterpret_cast<const float4*>(xr + k4 * 4);
        if (BN_IN) {
            const int c = k4 * 4;  // uniform
            xv.x = elu_f(xv.x * scale[c + 0] + shift[c + 0]);
            xv.y = elu_f(xv.y * scale[c + 1] + shift[c + 1]);
            xv.z = elu_f(xv.z * scale[c + 2] + shift[c + 2]);
            xv.w = elu_f(xv.w * scale[c + 3] + shift[c + 3]);
        }
#pragma unroll
        for (int j = 0; j < 4; ++j) {
            const float xk = (j == 0) ? xv.x : (j == 1) ? xv.y : (j == 2) ? xv.z : xv.w;
            const float4* Wk = reinterpret_cast<const float4*>(W + (size_t)(k4 * 4 + j) * 64);
#pragma unroll
            for (int f4 = 0; f4 < 16; ++f4) {
                float4 w = Wk[f4];
                acc[f4 * 4 + 0] = fmaf(xk, w.x, acc[f4 * 4 + 0]);
                acc[f4 * 4 + 1] = fmaf(xk, w.y, acc[f4 * 4 + 1]);
                acc[f4 * 4 + 2] = fmaf(xk, w.z, acc[f4 * 4 + 2]);
                acc[f4 * 4 + 3] = fmaf(xk, w.w, acc[f4 * 4 + 3]);
            }
        }
    }

    float* orow = out + (size_t)row * 64;
#pragma unroll
    for (int f4 = 0; f4 < 16; ++f4) {
        float4 v;
        v.x = ELU_OUT ? elu_f(acc[f4 * 4 + 0]) : acc[f4 * 4 + 0];
        v.y = ELU_OUT ? elu_f(acc[f4 * 4 + 1]) : acc[f4 * 4 + 1];
        v.z = ELU_OUT ? elu_f(acc[f4 * 4 + 2]) : acc[f4 * 4 + 2];
        v.w = ELU_OUT ? elu_f(acc[f4 * 4 + 3]) : acc[f4 * 4 + 3];
        *reinterpret_cast<float4*>(orow + f4 * 4) = v;
    }
}

// ---------------------------------------------------------------------------
// Head: out = relu([h1,h2] @ Wl1 + bl1) @ Wl2 + bl2
// lane = row; all acc[] indices compile-time static (rule #20).
// ---------------------------------------------------------------------------
__global__ __launch_bounds__(256) void k_final(const float* __restrict__ h1,
                                               const float* __restrict__ h2,
                                               const float* __restrict__ Wl1,
                                               const float* __restrict__ bl1,
                                               const float* __restrict__ Wl2,
                                               const float* __restrict__ bl2,
                                               float* __restrict__ out) {
    const int lane = threadIdx.x & 63;
    const int wid  = (blockIdx.x * blockDim.x + threadIdx.x) >> 6;
    const int row  = wid * 64 + lane;
    if (row >= N) return;

    float acc[64];
#pragma unroll
    for (int f = 0; f < 64; ++f) acc[f] = bl1[f];

#pragma unroll 1
    for (int half = 0; half < 2; ++half) {
        const float* xr = (half == 0 ? h1 : h2) + (size_t)row * 64;
        const float* Wh = Wl1 + (size_t)half * 64 * 64;
#pragma unroll 2
        for (int k4 = 0; k4 < 16; ++k4) {
            float4 xv = *reinterpret_cast<const float4*>(xr + k4 * 4);
#pragma unroll
            for (int j = 0; j < 4; ++j) {
                const float xk = (j == 0) ? xv.x : (j == 1) ? xv.y : (j == 2) ? xv.z : xv.w;
                const float4* Wk = reinterpret_cast<const float4*>(Wh + (size_t)(k4 * 4 + j) * 64);
#pragma unroll
                for (int f4 = 0; f4 < 16; ++f4) {
                    float4 w = Wk[f4];
                    acc[f4 * 4 + 0] = fmaf(xk, w.x, acc[f4 * 4 + 0]);
                    acc[f4 * 4 + 1] = fmaf(xk, w.y, acc[f4 * 4 + 1]);
                    acc[f4 * 4 + 2] = fmaf(xk, w.z, acc[f4 * 4 + 2]);
                    acc[f4 * 4 + 3] = fmaf(xk, w.w, acc[f4 * 4 + 3]);
                }
            }
        }
    }

    float acc2[16];
#pragma unroll
    for (int c = 0; c < 16; ++c) acc2[c] = bl2[c];
#pragma unroll
    for (int k = 0; k < 64; ++k) {
        float tk = fmaxf(acc[k], 0.f);
        const float4* Wk = reinterpret_cast<const float4*>(Wl2 + (size_t)k * 16);
#pragma unroll
        for (int c4 = 0; c4 < 4; ++c4) {
            float4 w = Wk[c4];
            acc2[c4 * 4 + 0] = fmaf(tk, w.x, acc2[c4 * 4 + 0]);
            acc2[c4 * 4 + 1] = fmaf(tk, w.y, acc2[c4 * 4 + 1]);
            acc2[c4 * 4 + 2] = fmaf(tk, w.z, acc2[c4 * 4 + 2]);
            acc2[c4 * 4 + 3] = fmaf(tk, w.w, acc2[c4 * 4 + 3]);
        }
    }

    float* orow = out + (size_t)row * 16;
#pragma unroll
    for (int c4 = 0; c4 < 4; ++c4) {
        float4 v;
        v.x = acc2[c4 * 4 + 0];
        v.y = acc2[c4 * 4 + 1];
        v.z = acc2[c4 * 4 + 2];
        v.w = acc2[c4 * 4 + 3];
        *reinterpret_cast<float4*>(orow + c4 * 4) = v;
    }
}

// ---------------------------------------------------------------------------
// Launch
// ---------------------------------------------------------------------------
extern "C" void kernel_launch(void* const* d_in, const int* in_sizes, int n_in,
                              void* d_out, int out_size, void* d_ws, size_t ws_size,
                              hipStream_t stream) {
    const float* x   = (const float*)d_in[0];
    const int*   ei  = (const int*)d_in[1];
    const int*   esrc = ei;       // edge_index[0]
    const int*   edst = ei + E;   // edge_index[1]
    const float* W1  = (const float*)d_in[2];
    const float* b1  = (const float*)d_in[3];
    const float* g1  = (const float*)d_in[4];
    const float* be1 = (const float*)d_in[5];
    const float* W2  = (const float*)d_in[6];
    const float* b2  = (const float*)d_in[7];
    const float* W3  = (const float*)d_in[8];
    const float* b3  = (const float*)d_in[9];
    const float* g2  = (const float*)d_in[10];
    const float* be2 = (const float*)d_in[11];
    const float* W4  = (const float*)d_in[12];
    const float* b4  = (const float*)d_in[13];
    const float* Wl1 = (const float*)d_in[14];
    const float* bl1 = (const float*)d_in[15];
    const float* Wl2 = (const float*)d_in[16];
    const float* bl2 = (const float*)d_in[17];
    float* out = (float*)d_out;

    // Workspace carve (aligned 256B)
    char* p = (char*)d_ws;
    auto carve = [&](size_t bytes) {
        void* r = (void*)p;
        p += (bytes + 255) & ~(size_t)255;
        return r;
    };
    constexpr size_t SROW = (size_t)N * H * sizeof(float);  // 25.6 MB
    float* y   = (float*)carve(SROW);
    float* z   = (float*)carve(SROW);
    float* h1  = (float*)carve(SROW);
    float* h2  = (float*)carve(SROW);
    int*   ebuf    = (int*)carve((size_t)NB * CAP * 4);     // 8.8 MB
    int*   gcur    = (int*)carve((size_t)NB * 4);
    int*   bbase   = (int*)carve((size_t)NB * 4);
    int*   row_ptr = (int*)carve((size_t)(N + 1) * 4);
    int*   csr     = (int*)carve((size_t)E * 4);            // 6.4 MB
    float* part    = (float*)carve((size_t)256 * 128 * 4);
    float* scale   = (float*)carve(64 * 4);
    float* shift   = (float*)carve(64 * 4);
    (void)ws_size; (void)in_sizes; (void)n_in; (void)out_size;

    constexpr int LINB = ((N + 63) / 64 + 3) / 4;           // 391
    constexpr int AGGB = (N * 64 + 255) / 256;              // 25000

    // CSR build via buckets (no random-scatter write amplification)
    k_initcur<<<1, 1024, 0, stream>>>(gcur);
    k_binfill<<<FBLK, 256, 0, stream>>>(esrc, edst, gcur, ebuf);
    k_bscan<<<1, 1024, 0, stream>>>(gcur, bbase, row_ptr);
    k_bsort<<<NB, 256, 0, stream>>>(ebuf, gcur, bbase, row_ptr, csr);

    // Layer 1: y = x@W1 ; z = y + agg(y) + b1 ; stats ; h1 = elu(bnelu(z)@W2 + b2)
    k_linear<128, false, false, false><<<LINB, 256, 0, stream>>>(x, W1, nullptr, nullptr, nullptr, y);
    k_agg<<<AGGB, 256, 0, stream>>>(y, row_ptr, csr, b1, z);
    k_stats1<<<256, 256, 0, stream>>>(z, part);
    k_stats2<<<1, 128, 0, stream>>>(part, g1, be1, scale, shift);
    k_linear<64, true, true, true><<<LINB, 256, 0, stream>>>(z, W2, b2, scale, shift, h1);

    // Layer 2
    k_linear<64, false, false, false><<<LINB, 256, 0, stream>>>(h1, W3, nullptr, nullptr, nullptr, y);
    k_agg<<<AGGB, 256, 0, stream>>>(y, row_ptr, csr, b3, z);
    k_stats1<<<256, 256, 0, stream>>>(z, part);
    k_stats2<<<1, 128, 0, stream>>>(part, g2, be2, scale, shift);
    k_linear<64, true, true, true><<<LINB, 256, 0, stream>>>(z, W4, b4, scale, shift, h2);

    // Head
    k_final<<<LINB, 256, 0, stream>>>(h1, h2, Wl1, bl1, Wl2, bl2, out);
}